// Round 2
// baseline (118.506 us; speedup 1.0000x reference)
//
#include <hip/hip_runtime.h>

// steps = 65536, channels = 6, state = [pos(6), vel(6)]
// Closed form of the scan:
//   S_t = sum_{i<=t} a_i        (per channel)
//   W_t = sum_{i<=t} i * a_i    (per channel)
//   vel[t] = v0 + dt*S_t
//   pos[t] = p0 + dt*(t+1)*v0 + dt^2*((t+0.5)*S_t - W_t)
// Output layout: states [65536,12] flat, then actions [65536,6] flat.
//
// SINGLE regular launch (graph-capturable — hipLaunchCooperativeKernel cost
// ~60us/iter in R1; the 256 MiB d_ws poison fill (~40us) is unconditional
// harness behavior and is the floor). Grid sync is a monotonic ticket barrier:
// grid = 256 blocks = 256 CUs (18 KiB LDS, low VGPR -> all co-resident), and
// stream ordering serializes launches, so every launch's 256 blocks take a
// contiguous ticket range [k*NB, (k+1)*NB) and wait for g_count to reach
// (k+1)*NB. No reset needed -> re-poison-safe and graph-replay-safe.
// g_bsum is rewritten every launch before the barrier; no stale-state dep.

#define STEPS   65536
#define NCH     6
#define STATE   12
#define NB      256
#define CHUNK   (STEPS / NB)        // 256 steps per block
#define BLK     (NCH * 64)          // 384 threads = 6 waves; wave w <-> channel w
#define ACT_OFF (STEPS * STATE)     // float offset of actions region in out

__device__ double             g_bsum[NB * NCH * 2];  // 24 KiB static scratch (NOT d_ws)
__device__ unsigned long long g_count = 0ULL;        // monotonic ticket counter

__global__ __launch_bounds__(BLK) void k_fused(const float4* __restrict__ act4,
                                               const float* __restrict__ x,
                                               float* __restrict__ out) {
    __shared__ float sIn[CHUNK * NCH];      // 6 KiB  — action chunk, persists across barrier
    __shared__ float sOut[CHUNK * STATE];   // 12 KiB — state chunk for coalesced writeout
    const int b = blockIdx.x, tid = threadIdx.x;

    // Coalesced stage-in + actions passthrough (coalesced float4 store).
    float4 v = act4[b * (CHUNK * NCH / 4) + tid];
    ((float4*)(out + ACT_OFF))[b * (CHUNK * NCH / 4) + tid] = v;
    ((float4*)sIn)[tid] = v;
    __syncthreads();

    const int c = tid >> 6, lane = tid & 63;

    // ---- Phase 1: per-(block,channel) partial sums ----
    {
        double sA = 0.0, sW = 0.0;
#pragma unroll
        for (int k = 0; k < 4; ++k) {
            const int   tl = k * 64 + lane;
            const float a  = sIn[tl * NCH + c];
            sA += (double)a;
            sW += (double)(b * CHUNK + tl) * (double)a;
        }
#pragma unroll
        for (int off = 32; off > 0; off >>= 1) {
            sA += __shfl_down(sA, off, 64);
            sW += __shfl_down(sW, off, 64);
        }
        if (lane == 0) {
            g_bsum[(b * NCH + c) * 2 + 0] = sA;
            g_bsum[(b * NCH + c) * 2 + 1] = sW;
        }
    }

    // ---- Device-scope ticket barrier (replaces grid.sync()) ----
    __threadfence();        // publish g_bsum writes device-wide (release side)
    __syncthreads();        // all waves' writes ordered before tid0's ticket
    if (tid == 0) {
        unsigned long long t = __hip_atomic_fetch_add(&g_count, 1ULL,
                                                      __ATOMIC_RELEASE,
                                                      __HIP_MEMORY_SCOPE_AGENT);
        const unsigned long long target = (t / NB + 1ULL) * NB;
        while (__hip_atomic_load(&g_count, __ATOMIC_ACQUIRE,
                                 __HIP_MEMORY_SCOPE_AGENT) < target) {
            __builtin_amdgcn_s_sleep(2);
        }
    }
    __syncthreads();        // release whole block after tid0 observed the barrier
    __threadfence();        // acquire side: no stale L2 lines for g_bsum reads

    // ---- Phase 2: cross-block exclusive prefix for this channel ----
    double offA, offW;
    {
        double vA = 0.0, vW = 0.0;
#pragma unroll
        for (int k = 0; k < 4; ++k) {
            const int idx = k * 64 + lane;
            if (idx < b) {
                vA += g_bsum[(idx * NCH + c) * 2 + 0];
                vW += g_bsum[(idx * NCH + c) * 2 + 1];
            }
        }
#pragma unroll
        for (int off = 32; off > 0; off >>= 1) {
            vA += __shfl_down(vA, off, 64);
            vW += __shfl_down(vW, off, 64);
        }
        offA = __shfl(vA, 0, 64);
        offW = __shfl(vW, 0, 64);
    }

    const double dt  = (double)0.1f;   // match float32(0.1) bit pattern
    const double dt2 = dt * dt;
    const double p0  = (double)x[c];
    const double v0  = (double)x[NCH + c];

    double accA = offA, accW = offW;   // running totals before current 64-tile
#pragma unroll
    for (int k = 0; k < 4; ++k) {
        const int   tl = k * 64 + lane;
        const int   t  = b * CHUNK + tl;
        const float a  = sIn[tl * NCH + c];
        double iA = (double)a;
        double iW = (double)t * (double)a;
        // Inclusive 64-lane scan (lane <-> t, stride 1).
#pragma unroll
        for (int off = 1; off < 64; off <<= 1) {
            const double uA = __shfl_up(iA, off, 64);
            const double uW = __shfl_up(iW, off, 64);
            if (lane >= off) { iA += uA; iW += uW; }
        }
        const double runA = accA + iA;
        const double runW = accW + iW;
        const double vel = v0 + dt * runA;
        const double pos = p0 + dt * (double)(t + 1) * v0
                         + dt2 * (((double)t + 0.5) * runA - runW);
        sOut[tl * STATE + c]       = (float)pos;
        sOut[tl * STATE + NCH + c] = (float)vel;
        accA += __shfl(iA, 63, 64);    // add tile total
        accW += __shfl(iW, 63, 64);
    }
    __syncthreads();

    // Coalesced writeout of the 256x12 state chunk: 768 float4, 2/thread.
    const float4* so4 = (const float4*)sOut;
    float4*       o4  = (float4*)out;
    o4[b * (CHUNK * STATE / 4) + tid]       = so4[tid];
    o4[b * (CHUNK * STATE / 4) + BLK + tid] = so4[BLK + tid];
}

extern "C" void kernel_launch(void* const* d_in, const int* in_sizes, int n_in,
                              void* d_out, int out_size, void* d_ws, size_t ws_size,
                              hipStream_t stream) {
    const float*  x    = (const float*)d_in[0];   // 12 floats: pos(6), vel(6)
    const float4* act4 = (const float4*)d_in[1];  // [65536, 6] as float4
    float*        out  = (float*)d_out;           // states(786432) + actions(393216)

    hipLaunchKernelGGL(k_fused, dim3(NB), dim3(BLK), 0, stream,
                       act4, x, out);
}

// Round 3
// 65.674 us; speedup vs baseline: 1.8044x; 1.8044x over previous
//
#include <hip/hip_runtime.h>

// steps = 65536, channels = 6, state = [pos(6), vel(6)]
// Closed form of the scan:
//   S_t = sum_{i<=t} a_i        (per channel)
//   W_t = sum_{i<=t} i * a_i    (per channel)
//   vel[t] = v0 + dt*S_t
//   pos[t] = p0 + dt*(t+1)*v0 + dt^2*((t+0.5)*S_t - W_t)
// Output layout: states [65536,12] flat, then actions [65536,6] flat.
//
// SINGLE regular launch (graph-capturable). Known-unconditional costs in the
// timed region: 256 MiB d_ws poison fill ~40.4us + out poison ~0.7us.
//
// R2 lesson: device-scope __threadfence (buffer_wbl2) x 1536 waves x2 and an
// ACQUIRE spin load (L2-invalidate per poll) made the grid barrier cost 68us
// at 1.2% VALUBusy. This version uses NO fences and NO acquire/release:
// every cross-block datum (g_bsum, g_count) is an agent-scope RELAXED atomic,
// which the HW routes past the non-coherent per-XCD L2 to the coherence
// point. Ordering: __syncthreads() drains vmcnt(0) (compiler-guaranteed
// before s_barrier), so each block's g_bsum atomic stores are acked at the
// coherence point BEFORE its ticket fetch_add issues; g_count==target under a
// relaxed load therefore implies all 256 blocks' partials are visible to
// relaxed atomic loads. Ticket is monotonic: launches are stream-serialized,
// so each launch's 256 blocks take a contiguous ticket range [k*NB,(k+1)*NB)
// and wait for (k/NB+1)*NB. No reset -> re-poison-safe, graph-replay-safe.
// Liveness: 256 blocks, 18 KiB LDS, ~32 VGPR -> capacity >= 2 blocks/CU, so
// all 256 blocks are resident under any packing; no deadlock.

#define STEPS   65536
#define NCH     6
#define STATE   12
#define NB      256
#define CHUNK   (STEPS / NB)        // 256 steps per block
#define BLK     (NCH * 64)          // 384 threads = 6 waves; wave w <-> channel w
#define ACT_OFF (STEPS * STATE)     // float offset of actions region in out

__device__ double             g_bsum[NB * NCH * 2];  // static scratch (NOT d_ws)
__device__ unsigned long long g_count = 0ULL;        // monotonic ticket counter

__global__ __launch_bounds__(BLK) void k_fused(const float4* __restrict__ act4,
                                               const float* __restrict__ x,
                                               float* __restrict__ out) {
    __shared__ float sIn[CHUNK * NCH];      // 6 KiB  — action chunk, persists across barrier
    __shared__ float sOut[CHUNK * STATE];   // 12 KiB — state chunk for coalesced writeout
    const int b = blockIdx.x, tid = threadIdx.x;

    // Coalesced stage-in (passthrough store deferred to after the barrier so
    // the pre-barrier vmcnt drain only covers the tiny g_bsum atomics).
    float4 v = act4[b * (CHUNK * NCH / 4) + tid];
    ((float4*)sIn)[tid] = v;
    __syncthreads();

    const int c = tid >> 6, lane = tid & 63;

    // ---- Phase 1: per-(block,channel) partial sums ----
    {
        double sA = 0.0, sW = 0.0;
#pragma unroll
        for (int k = 0; k < 4; ++k) {
            const int   tl = k * 64 + lane;
            const float a  = sIn[tl * NCH + c];
            sA += (double)a;
            sW += (double)(b * CHUNK + tl) * (double)a;
        }
#pragma unroll
        for (int off = 32; off > 0; off >>= 1) {
            sA += __shfl_down(sA, off, 64);
            sW += __shfl_down(sW, off, 64);
        }
        if (lane == 0) {
            __hip_atomic_store(&g_bsum[(b * NCH + c) * 2 + 0], sA,
                               __ATOMIC_RELAXED, __HIP_MEMORY_SCOPE_AGENT);
            __hip_atomic_store(&g_bsum[(b * NCH + c) * 2 + 1], sW,
                               __ATOMIC_RELAXED, __HIP_MEMORY_SCOPE_AGENT);
        }
    }

    // ---- Ticket barrier: relaxed atomics only, no fences ----
    __syncthreads();    // drains vmcnt(0): g_bsum stores acked before ticket
    if (tid == 0) {
        unsigned long long t = __hip_atomic_fetch_add(&g_count, 1ULL,
                                                      __ATOMIC_RELAXED,
                                                      __HIP_MEMORY_SCOPE_AGENT);
        const unsigned long long target = (t / NB + 1ULL) * NB;
        while (__hip_atomic_load(&g_count, __ATOMIC_RELAXED,
                                 __HIP_MEMORY_SCOPE_AGENT) < target) {
            __builtin_amdgcn_s_sleep(2);
        }
    }
    __syncthreads();    // release the whole block

    // Actions passthrough (independent of barrier; overlaps phase 2).
    ((float4*)(out + ACT_OFF))[b * (CHUNK * NCH / 4) + tid] = v;

    // ---- Phase 2: cross-block exclusive prefix for this channel ----
    double offA, offW;
    {
        double vA = 0.0, vW = 0.0;
#pragma unroll
        for (int k = 0; k < 4; ++k) {
            const int idx = k * 64 + lane;
            if (idx < b) {
                vA += __hip_atomic_load(&g_bsum[(idx * NCH + c) * 2 + 0],
                                        __ATOMIC_RELAXED, __HIP_MEMORY_SCOPE_AGENT);
                vW += __hip_atomic_load(&g_bsum[(idx * NCH + c) * 2 + 1],
                                        __ATOMIC_RELAXED, __HIP_MEMORY_SCOPE_AGENT);
            }
        }
#pragma unroll
        for (int off = 32; off > 0; off >>= 1) {
            vA += __shfl_down(vA, off, 64);
            vW += __shfl_down(vW, off, 64);
        }
        offA = __shfl(vA, 0, 64);
        offW = __shfl(vW, 0, 64);
    }

    const double dt  = (double)0.1f;   // match float32(0.1) bit pattern
    const double dt2 = dt * dt;
    const double p0  = (double)x[c];
    const double v0  = (double)x[NCH + c];

    double accA = offA, accW = offW;   // running totals before current 64-tile
#pragma unroll
    for (int k = 0; k < 4; ++k) {
        const int   tl = k * 64 + lane;
        const int   t  = b * CHUNK + tl;
        const float a  = sIn[tl * NCH + c];
        double iA = (double)a;
        double iW = (double)t * (double)a;
        // Inclusive 64-lane scan (lane <-> t, stride 1).
#pragma unroll
        for (int off = 1; off < 64; off <<= 1) {
            const double uA = __shfl_up(iA, off, 64);
            const double uW = __shfl_up(iW, off, 64);
            if (lane >= off) { iA += uA; iW += uW; }
        }
        const double runA = accA + iA;
        const double runW = accW + iW;
        const double vel = v0 + dt * runA;
        const double pos = p0 + dt * (double)(t + 1) * v0
                         + dt2 * (((double)t + 0.5) * runA - runW);
        sOut[tl * STATE + c]       = (float)pos;
        sOut[tl * STATE + NCH + c] = (float)vel;
        accA += __shfl(iA, 63, 64);    // add tile total
        accW += __shfl(iW, 63, 64);
    }
    __syncthreads();

    // Coalesced writeout of the 256x12 state chunk: 768 float4, 2/thread.
    const float4* so4 = (const float4*)sOut;
    float4*       o4  = (float4*)out;
    o4[b * (CHUNK * STATE / 4) + tid]       = so4[tid];
    o4[b * (CHUNK * STATE / 4) + BLK + tid] = so4[BLK + tid];
}

extern "C" void kernel_launch(void* const* d_in, const int* in_sizes, int n_in,
                              void* d_out, int out_size, void* d_ws, size_t ws_size,
                              hipStream_t stream) {
    const float*  x    = (const float*)d_in[0];   // 12 floats: pos(6), vel(6)
    const float4* act4 = (const float4*)d_in[1];  // [65536, 6] as float4
    float*        out  = (float*)d_out;           // states(786432) + actions(393216)

    hipLaunchKernelGGL(k_fused, dim3(NB), dim3(BLK), 0, stream,
                       act4, x, out);
}

// Round 4
// 63.614 us; speedup vs baseline: 1.8629x; 1.0324x over previous
//
#include <hip/hip_runtime.h>

// steps = 65536, channels = 6, state = [pos(6), vel(6)]
// Closed form of the scan:
//   S_t = sum_{i<=t} a_i        (per channel)
//   W_t = sum_{i<=t} i * a_i    (per channel)
//   vel[t] = v0 + dt*S_t
//   pos[t] = p0 + dt*(t+1)*v0 + dt^2*((t+0.5)*S_t - W_t)
// Output layout: states [65536,12] flat, then actions [65536,6] flat.
//
// SINGLE regular launch (graph-capturable). Unconditional harness costs in
// the timed region: 256 MiB d_ws poison ~40.4us + out poison ~0.7us + ~9us
// of inter-dispatch gaps. Controllable part = this kernel.
//
// Barrier history: R2 (fences + acquire spin) = 68us. R3 (relaxed atomics,
// single shared ticket line) = ~15us — diagnosis: 256 fetch_add arrivals and
// 256 pollers hammering ONE cacheline at the coherence point; arrivals queue
// behind the poll storm. This version: DISTRIBUTED FLAG BARRIER.
//   - arrival: relaxed fetch_add on the block's OWN flag (64B-padded line,
//     uncontended). Epoch e = old+1 is launch-uniform: stream ordering means
//     all flags are equal at every launch boundary (monotonic, no reset ->
//     graph-replay-safe and re-poison-safe; zero-init handles launch 0).
//   - wait: wave 0 sweeps the 256 flags (lane L owns L, L+64, L+128, L+192),
//     clearing satisfied flags from a pending mask, s_sleep between sweeps.
//     Poll traffic is spread over 256 lines -> no single-line RMW starvation.
// Ordering (verified mechanism from R3, which passed): __syncthreads drains
// vmcnt(0) before s_barrier, so g_bsum relaxed-atomic stores are acked at the
// coherence point BEFORE the flag RMW issues; observing flag[i] >= e under a
// relaxed load implies block i's partials are visible to relaxed atomic loads.
// Liveness: 256 blocks, 18 KiB LDS, ~32 VGPR -> all blocks co-resident.

#define STEPS   65536
#define NCH     6
#define STATE   12
#define NB      256
#define CHUNK   (STEPS / NB)        // 256 steps per block
#define BLK     (NCH * 64)          // 384 threads = 6 waves; wave w <-> channel w
#define ACT_OFF (STEPS * STATE)     // float offset of actions region in out

__device__ double             g_bsum[NB * NCH * 2];   // static scratch (NOT d_ws)
__device__ unsigned long long g_flag[NB * 8];         // per-block epoch flags, 64B apart

__global__ __launch_bounds__(BLK) void k_fused(const float4* __restrict__ act4,
                                               const float* __restrict__ x,
                                               float* __restrict__ out) {
    __shared__ float sIn[CHUNK * NCH];      // 6 KiB  — action chunk, persists across barrier
    __shared__ float sOut[CHUNK * STATE];   // 12 KiB — state chunk for coalesced writeout
    __shared__ unsigned long long sEpoch;
    const int b = blockIdx.x, tid = threadIdx.x;

    // Coalesced stage-in (passthrough store deferred to after the barrier so
    // the pre-barrier vmcnt drain only covers the tiny g_bsum atomics).
    float4 v = act4[b * (CHUNK * NCH / 4) + tid];
    ((float4*)sIn)[tid] = v;
    __syncthreads();

    const int c = tid >> 6, lane = tid & 63;

    // ---- Phase 1: per-(block,channel) partial sums ----
    {
        double sA = 0.0, sW = 0.0;
#pragma unroll
        for (int k = 0; k < 4; ++k) {
            const int   tl = k * 64 + lane;
            const float a  = sIn[tl * NCH + c];
            sA += (double)a;
            sW += (double)(b * CHUNK + tl) * (double)a;
        }
#pragma unroll
        for (int off = 32; off > 0; off >>= 1) {
            sA += __shfl_down(sA, off, 64);
            sW += __shfl_down(sW, off, 64);
        }
        if (lane == 0) {
            __hip_atomic_store(&g_bsum[(b * NCH + c) * 2 + 0], sA,
                               __ATOMIC_RELAXED, __HIP_MEMORY_SCOPE_AGENT);
            __hip_atomic_store(&g_bsum[(b * NCH + c) * 2 + 1], sW,
                               __ATOMIC_RELAXED, __HIP_MEMORY_SCOPE_AGENT);
        }
    }

    // ---- Distributed flag barrier ----
    __syncthreads();            // drains vmcnt(0): g_bsum stores acked at LLC
    if (tid == 0) {
        unsigned long long old = __hip_atomic_fetch_add(&g_flag[b * 8], 1ULL,
                                                        __ATOMIC_RELAXED,
                                                        __HIP_MEMORY_SCOPE_AGENT);
        sEpoch = old + 1ULL;    // launch-uniform epoch
    }
    __syncthreads();
    const unsigned long long e = sEpoch;
    if (tid < 64) {
        unsigned pend = 0xFu;   // lane owns flags lane, lane+64, lane+128, lane+192
        for (;;) {
#pragma unroll
            for (int j = 0; j < 4; ++j) {
                if (pend & (1u << j)) {
                    unsigned long long f =
                        __hip_atomic_load(&g_flag[(lane + 64 * j) * 8],
                                          __ATOMIC_RELAXED,
                                          __HIP_MEMORY_SCOPE_AGENT);
                    if (f >= e) pend &= ~(1u << j);
                }
            }
            if (__all(pend == 0u)) break;
            __builtin_amdgcn_s_sleep(4);
        }
    }
    __syncthreads();            // release all 6 waves

    // Actions passthrough (independent of barrier; overlaps phase 2).
    ((float4*)(out + ACT_OFF))[b * (CHUNK * NCH / 4) + tid] = v;

    // ---- Phase 2: cross-block exclusive prefix for this channel ----
    double offA, offW;
    {
        double vA = 0.0, vW = 0.0;
#pragma unroll
        for (int k = 0; k < 4; ++k) {
            const int idx = k * 64 + lane;
            if (idx < b) {
                vA += __hip_atomic_load(&g_bsum[(idx * NCH + c) * 2 + 0],
                                        __ATOMIC_RELAXED, __HIP_MEMORY_SCOPE_AGENT);
                vW += __hip_atomic_load(&g_bsum[(idx * NCH + c) * 2 + 1],
                                        __ATOMIC_RELAXED, __HIP_MEMORY_SCOPE_AGENT);
            }
        }
#pragma unroll
        for (int off = 32; off > 0; off >>= 1) {
            vA += __shfl_down(vA, off, 64);
            vW += __shfl_down(vW, off, 64);
        }
        offA = __shfl(vA, 0, 64);
        offW = __shfl(vW, 0, 64);
    }

    const double dt  = (double)0.1f;   // match float32(0.1) bit pattern
    const double dt2 = dt * dt;
    const double p0  = (double)x[c];
    const double v0  = (double)x[NCH + c];

    double accA = offA, accW = offW;   // running totals before current 64-tile
#pragma unroll
    for (int k = 0; k < 4; ++k) {
        const int   tl = k * 64 + lane;
        const int   t  = b * CHUNK + tl;
        const float a  = sIn[tl * NCH + c];
        double iA = (double)a;
        double iW = (double)t * (double)a;
        // Inclusive 64-lane scan (lane <-> t, stride 1).
#pragma unroll
        for (int off = 1; off < 64; off <<= 1) {
            const double uA = __shfl_up(iA, off, 64);
            const double uW = __shfl_up(iW, off, 64);
            if (lane >= off) { iA += uA; iW += uW; }
        }
        const double runA = accA + iA;
        const double runW = accW + iW;
        const double vel = v0 + dt * runA;
        const double pos = p0 + dt * (double)(t + 1) * v0
                         + dt2 * (((double)t + 0.5) * runA - runW);
        sOut[tl * STATE + c]       = (float)pos;
        sOut[tl * STATE + NCH + c] = (float)vel;
        accA += __shfl(iA, 63, 64);    // add tile total
        accW += __shfl(iW, 63, 64);
    }
    __syncthreads();

    // Coalesced writeout of the 256x12 state chunk: 768 float4, 2/thread.
    const float4* so4 = (const float4*)sOut;
    float4*       o4  = (float4*)out;
    o4[b * (CHUNK * STATE / 4) + tid]       = so4[tid];
    o4[b * (CHUNK * STATE / 4) + BLK + tid] = so4[BLK + tid];
}

extern "C" void kernel_launch(void* const* d_in, const int* in_sizes, int n_in,
                              void* d_out, int out_size, void* d_ws, size_t ws_size,
                              hipStream_t stream) {
    const float*  x    = (const float*)d_in[0];   // 12 floats: pos(6), vel(6)
    const float4* act4 = (const float4*)d_in[1];  // [65536, 6] as float4
    float*        out  = (float*)d_out;           // states(786432) + actions(393216)

    hipLaunchKernelGGL(k_fused, dim3(NB), dim3(BLK), 0, stream,
                       act4, x, out);
}